// Round 1
// baseline (910.033 us; speedup 1.0000x reference)
//
#include <hip/hip_runtime.h>

// Neural stack unroll: T=512 steps, B=128 batches, E=256.
// One block per batch: wave0/lane0 = stack sim (register top-window + LDS deep
// stack), wave1 = 64 float4 workers consuming double-buffered coeff lists.
// Exactness: coeffs are provably zero once cumulative strength from top >= 1;
// zero-strength entries are transparent (add exactly 0.0) so compact storage
// and skipping match the dense reference bit-for-bit up to fp association.

#define TT 512
#define BB 128
#define EE 256
#define W  12       // register window depth for pop/read walks
#define MAXBIG 520  // coeff list capacity (worst-case whole stack + pad)

__launch_bounds__(128, 1)
__global__ void stack_kernel(const float* __restrict__ v,
                             const float* __restrict__ u,
                             const float* __restrict__ d,
                             float* __restrict__ out) {
  const int b = blockIdx.x;
  const int tid = threadIdx.x;

  __shared__ float ss[TT];          // stack strengths (compact, bottom-up)
  __shared__ int   si[TT];          // absolute slot index (timestep pushed)
  __shared__ float cf[2][MAXBIG];   // double-buffered coeff list
  __shared__ int   ci[2][MAXBIG];   // row offsets (i*B*E), double-buffered
  __shared__ int   nl[2];           // padded list length

  int sp = 0;                       // stack size (sim thread only)
  float ut = u[b];                  // prefetched u[t], d[t] for this batch
  float dt = d[b];

  const int lane = tid - 64;        // worker lane (wave 1)

  for (int t = 0; t <= TT; ++t) {
    // ---- sim: produce list for step t (concurrent with workers doing t-1) --
    if (tid == 0 && t < TT) {
      const float cut = ut;
      const float cdt = dt;
      const int tn = (t + 1 < TT) ? (t + 1) : t;
      ut = u[tn * BB + b];          // issue next-step loads early (latency hidden)
      dt = d[tn * BB + b];

      const int buf = t & 1;
      int n = 0;

      // prefetch top-W window into registers (batched independent LDS reads)
      const int spw = sp < W ? sp : W;
      float w[W]; int wi[W];
#pragma unroll
      for (int j = 0; j < W; ++j) {
        int k = sp - 1 - j;
        int kk = k < 0 ? 0 : k;
        float sv = ss[kk];
        int   iv = si[kk];
        w[j]  = (j < spw) ? sv : 0.f;
        wi[j] = (j < spw) ? iv : 0;
      }

      // pop phase, prefix-scan form of the reference recurrence (all-register):
      // w_i = relu(u - P_i), s' = relu(s - w_i), P = prefix of OLD values top-down
      float P = 0.f;
#pragma unroll
      for (int j = 0; j < W; ++j) {
        float wt = cut - P;
        P += w[j];
        float sn = w[j] - fmaxf(wt, 0.f);
        w[j] = fmaxf(sn, 0.f);
      }

      if (P < cut && sp > W) {
        // ---- rare slow path: pop reaches below the window; do full serial step
        float cum = 0.f; int newsp = sp;
        for (int k = sp - 1; k >= 0; --k) {
          float wt = cut - cum;
          if (wt <= 0.f) break;
          float so = ss[k]; cum += so;
          float sn = so - wt;
          if (sn <= 0.f) newsp = k;       // fully popped through k
          else { ss[k] = sn; break; }     // partial pop, stop
        }
        sp = newsp;
        ss[sp] = cdt; si[sp] = t; sp++;
        float C = 0.f;
        for (int k = sp - 1; k >= 0 && n < MAXBIG - 8; --k) {
          float rem = 1.f - C;
          if (rem <= 0.f) break;
          float s = ss[k];
          float c = fminf(s, rem);
          if (c > 0.f) { cf[buf][n] = c; ci[buf][n] = si[k] * (BB * EE); n++; }
          C += s;
        }
      } else {
        // count fully-popped (leading zeros from top)
        int nz = W;
#pragma unroll
        for (int j = W - 1; j >= 0; --j) if (w[j] > 0.f) nz = j;
        int npop = nz < spw ? nz : spw;
        // write back modified window (zeros above new top are dead cells)
#pragma unroll
        for (int j = 0; j < W; ++j) {
          if (j < spw) ss[sp - 1 - j] = w[j];
        }
        const int spo = sp;
        sp -= npop;
        ss[sp] = cdt; si[sp] = t; sp++;

        // read phase: coeffs top-down until cumulative >= 1 (zeros transparent)
        float C = cdt;
        if (cdt > 0.f) { cf[buf][n] = fminf(cdt, 1.f); ci[buf][n] = t * (BB * EE); n++; }
#pragma unroll
        for (int j = 0; j < W; ++j) {
          float rem = 1.f - C;
          float c = fminf(w[j], fmaxf(rem, 0.f));
          if (c > 0.f) { cf[buf][n] = c; ci[buf][n] = wi[j] * (BB * EE); n++; }
          C += w[j];
        }
        if (C < 1.f) {
          // tail below the window (rare): serial LDS walk
          for (int k = spo - 1 - W; k >= 0 && n < MAXBIG - 8; --k) {
            float rem = 1.f - C;
            if (rem <= 0.f) break;
            float s = ss[k];
            float c = fminf(s, rem);
            if (c > 0.f) { cf[buf][n] = c; ci[buf][n] = si[k] * (BB * EE); n++; }
            C += s;
          }
        }
      }
      // pad to multiple of 8 so workers run a fixed-width unrolled loop
      int npad = (n + 7) & ~7;
      for (int q = n; q < npad; ++q) { cf[buf][q] = 0.f; ci[buf][q] = 0; }
      nl[buf] = npad;
    }

    // ---- workers: consume list for step t-1 (runs concurrently with sim) ----
    if (tid >= 64 && t >= 1) {
      const int tt2 = t - 1;
      const int buf = tt2 & 1;
      const int n = nl[buf];
      float4 r; r.x = 0.f; r.y = 0.f; r.z = 0.f; r.w = 0.f;
      const float* vb = v + b * EE;
      for (int k = 0; k < n; k += 8) {
#pragma unroll
        for (int j = 0; j < 8; ++j) {
          float c = cf[buf][k + j];
          int off = ci[buf][k + j];
          float4 x = ((const float4*)(vb + off))[lane];
          r.x += c * x.x; r.y += c * x.y; r.z += c * x.z; r.w += c * x.w;
        }
      }
      ((float4*)(out + (tt2 * BB + b) * EE))[lane] = r;
    }

    __syncthreads();  // single barrier/step: publishes list t, protects buf reuse
  }
}

extern "C" void kernel_launch(void* const* d_in, const int* in_sizes, int n_in,
                              void* d_out, int out_size, void* d_ws, size_t ws_size,
                              hipStream_t stream) {
  const float* v = (const float*)d_in[0];
  const float* u = (const float*)d_in[1];
  const float* dd = (const float*)d_in[2];
  float* out = (float*)d_out;
  (void)in_sizes; (void)n_in; (void)out_size; (void)d_ws; (void)ws_size;
  hipLaunchKernelGGL(stack_kernel, dim3(BB), dim3(128), 0, stream,
                     v, u, dd, out);
}